// Round 2
// baseline (2570.518 us; speedup 1.0000x reference)
//
#include <hip/hip_runtime.h>

#define B_ 128
#define T_ 270
#define XR 4104   // 8 + 64*64

typedef __attribute__((ext_vector_type(8))) short short8v;
typedef __attribute__((ext_vector_type(4))) float f32x4;

__device__ inline unsigned short f2bf(float f) {
  unsigned u = __builtin_bit_cast(unsigned, f);
  u += 0x7fffu + ((u >> 16) & 1u);
  return (unsigned short)(u >> 16);
}
__device__ inline float sigm(float x) { return 1.0f / (1.0f + __expf(-x)); }
__device__ inline float tanh_f(float x) {
  float t = __expf(-2.0f * fabsf(x));
  float r = (1.0f - t) / (1.0f + t);
  return copysignf(r, x);
}

// ---------------------------------------------------------------------------
// Kernel 1: per-(b,t) CNN tower. One block per image. Unchanged except it now
// zeroes the per-block step flags (block 0) instead of the old counters.
// ---------------------------------------------------------------------------
__global__ __launch_bounds__(256) void cnn_kernel(
    const float* __restrict__ x,
    const float* __restrict__ c1w_, const float* __restrict__ c1b_,
    const float* __restrict__ c2w_, const float* __restrict__ c2b_,
    const float* __restrict__ fcw, const float* __restrict__ fcb,
    const float* __restrict__ hdb,
    float* __restrict__ feat, unsigned* __restrict__ flags,
    float* __restrict__ out)
{
  __shared__ float img[64 * 68];
  __shared__ float p1[2 * 15 * 16];
  __shared__ float p2[36];
  __shared__ float wsm[96];
  const int tid = threadIdx.x;
  const int bt = blockIdx.x;
  const int b = bt & 127, t = bt >> 7;

  if (bt == 0 && tid < 32) flags[tid * 16] = 0;   // re-zero step flags per launch

  const float* src = x + ((long)b * T_ + t) * XR;

  if (tid < 18) wsm[tid] = c1w_[tid];
  else if (tid < 20) wsm[tid] = c1b_[tid - 18];
  else if (tid < 92) wsm[tid] = c2w_[tid - 20];
  else if (tid < 96) wsm[tid] = c2b_[tid - 92];

  {
    const float4* s4 = (const float4*)(src + 8);
#pragma unroll
    for (int i0 = 0; i0 < 4; i0++) {
      int i = tid + i0 * 256;
      float4 v = s4[i];
      int e = i * 4;
      *((float4*)&img[(e >> 6) * 68 + (e & 63)]) = v;
    }
  }
  __syncthreads();

  if (tid < 225) {
    int py = tid / 15, px = tid - (tid / 15) * 15;
    float w0[9], w1[9];
#pragma unroll
    for (int j = 0; j < 9; j++) { w0[j] = wsm[j]; w1[j] = wsm[9 + j]; }
    const float b0 = wsm[18], b1v = wsm[19];
    float m0 = -1e30f, m1 = -1e30f;
    for (int dy = 0; dy < 4; dy++) {
      for (int dx = 0; dx < 4; dx++) {
        const float* ip = &img[(py * 4 + dy) * 68 + px * 4 + dx];
        float s0 = b0, s1 = b1v;
#pragma unroll
        for (int ky = 0; ky < 3; ky++) {
#pragma unroll
          for (int kx = 0; kx < 3; kx++) {
            float v = ip[ky * 68 + kx];
            s0 = fmaf(v, w0[ky * 3 + kx], s0);
            s1 = fmaf(v, w1[ky * 3 + kx], s1);
          }
        }
        m0 = fmaxf(m0, s0); m1 = fmaxf(m1, s1);
      }
    }
    p1[py * 16 + px] = fmaxf(m0, 0.f);
    p1[240 + py * 16 + px] = fmaxf(m1, 0.f);
  }
  __syncthreads();

  if (tid < 36) {
    int ch = tid / 9, rem = tid - ch * 9;
    int py = rem / 3, px = rem - py * 3;
    float m = -1e30f;
    for (int dy = 0; dy < 4; dy++) {
      for (int dx = 0; dx < 4; dx++) {
        int y = py * 4 + dy, xx = px * 4 + dx;
        float s = wsm[92 + ch];
#pragma unroll
        for (int ic = 0; ic < 2; ic++)
#pragma unroll
          for (int ky = 0; ky < 3; ky++)
#pragma unroll
            for (int kx = 0; kx < 3; kx++)
              s = fmaf(p1[ic * 240 + (y + ky) * 16 + xx + kx],
                       wsm[20 + ((ch * 2 + ic) * 3 + ky) * 3 + kx], s);
        m = fmaxf(m, s);
      }
    }
    p2[tid] = fmaxf(m, 0.f);
  }
  __syncthreads();

  float* fr = feat + ((long)t * B_ + b) * 16;
  if (tid < 8) {
    float s = fcb[tid];
#pragma unroll
    for (int j = 0; j < 36; j++) s = fmaf(p2[j], fcw[tid * 36 + j], s);
    fr[8 + tid] = s;
  } else if (tid < 16) {
    fr[tid - 8] = src[tid - 8];
  } else if (tid == 16) {
    out[(long)b * T_ + t] = hdb[0];
  }
}

// ---------------------------------------------------------------------------
// Kernel 2: LSTM recurrence. 32 blocks; gb = blk&7 (XCD-local group under
// round-robin dispatch), hbk = blk>>3. Per-block monotonic step flags replace
// the fetch_add counter barrier. Own-slice + feat MFMAs computed before the
// wait; peer h slices loaded with relaxed agent atomics after a wave-level
// flag poll + acquire fence.
// ---------------------------------------------------------------------------
__global__ __launch_bounds__(256, 1) void lstm_kernel(
    const float* __restrict__ feat, const float* __restrict__ whh,
    const float* __restrict__ wih, const float* __restrict__ bih,
    const float* __restrict__ bhh, const float* __restrict__ h0,
    const float* __restrict__ c0, const float* __restrict__ hw,
    unsigned* hb0, unsigned* hb1, unsigned* flags, float* __restrict__ out)
{
  const int tid = threadIdx.x;
  const int wv = tid >> 6, lane = tid & 63;
  const int gb = blockIdx.x & 7;      // batch group 0..7 (rows gb*16..+15)
  const int hbk = blockIdx.x >> 3;    // hidden tile 0..3 (dims hbk*64..+63)
  const int R0 = gb * 16, D0 = hbk * 64;
  __shared__ float gates[16 * 256];
  __shared__ unsigned short hsl[16 * 88];   // own h slice (bf16), stride 88

  // ---- B-fragments: wave wv = gate wv, cols nt*16+(lane&15) of 64 dims.
  const int col15 = lane & 15, ko = (lane >> 4) * 8;
  short8v bf[4][9];
  for (int nt = 0; nt < 4; nt++) {
    int gr = wv * 256 + D0 + nt * 16 + col15;
    const float* wr = whh + gr * 256;
#pragma unroll
    for (int kf = 0; kf < 8; kf++) {
      const float4* wp = (const float4*)(wr + kf * 32 + ko);
      float4 a = wp[0], bq = wp[1];
      short8v v;
      v[0] = f2bf(a.x); v[1] = f2bf(a.y); v[2] = f2bf(a.z); v[3] = f2bf(a.w);
      v[4] = f2bf(bq.x); v[5] = f2bf(bq.y); v[6] = f2bf(bq.z); v[7] = f2bf(bq.w);
      bf[nt][kf] = v;
    }
    short8v v = {0, 0, 0, 0, 0, 0, 0, 0};
    if (ko < 16) {   // 9th K-frag: w_ih (K slots 256..271)
      const float4* wp = (const float4*)(wih + gr * 16 + ko);
      float4 a = wp[0], bq = wp[1];
      v[0] = f2bf(a.x); v[1] = f2bf(a.y); v[2] = f2bf(a.z); v[3] = f2bf(a.w);
      v[4] = f2bf(bq.x); v[5] = f2bf(bq.y); v[6] = f2bf(bq.z); v[7] = f2bf(bq.w);
    }
    bf[nt][8] = v;
  }

  // ---- elementwise-thread mapping: rows er+{0,8}, dims dl2, dl2+1
  const int dl2 = (tid & 31) * 2, er = tid >> 5;
  float cst[2][2];
  float bsr[4][2], hwr[2];
#pragma unroll
  for (int g = 0; g < 4; g++) {
    int grr = g * 256 + D0 + dl2;
    bsr[g][0] = bih[grr] + bhh[grr];
    bsr[g][1] = bih[grr + 1] + bhh[grr + 1];
  }
  hwr[0] = hw[D0 + dl2]; hwr[1] = hw[D0 + dl2 + 1];
#pragma unroll
  for (int p = 0; p < 2; p++) {
    int r = er + 8 * p;
    cst[p][0] = c0[(R0 + r) * 256 + D0 + dl2];
    cst[p][1] = c0[(R0 + r) * 256 + D0 + dl2 + 1];
    unsigned lo = f2bf(h0[(R0 + r) * 256 + D0 + dl2]);
    unsigned hi = f2bf(h0[(R0 + r) * 256 + D0 + dl2 + 1]);
    unsigned pk = lo | (hi << 16);
    __hip_atomic_store(hb0 + (R0 + r) * 128 + ((D0 + dl2) >> 1), pk,
                       __ATOMIC_RELAXED, __HIP_MEMORY_SCOPE_AGENT);
    *(unsigned*)&hsl[r * 88 + dl2] = pk;
  }
  __syncthreads();   // drains vmcnt: h0 stores acked before flag
  unsigned* myflag = flags + (gb * 4 + hbk) * 16;
  if (tid == 0)
    __hip_atomic_store(myflag, 1u, __ATOMIC_RELEASE, __HIP_MEMORY_SCOPE_AGENT);

  unsigned* hbr = hb0;
  unsigned* hbw = hb1;
  const int ar = lane & 15;           // A-fragment row
  const int kfOwn = 2 * hbk;
  unsigned* pollp = flags + (gb * 4 + (lane & 3)) * 16;

  for (int t = 0; t < T_; t++) {
    // ---- feat A-frag (global, no dependency) + own-slice A-frags (LDS)
    short8v af8 = {0, 0, 0, 0, 0, 0, 0, 0};
    if (ko < 16) {
      const float4* fp = (const float4*)(feat + ((long)t * B_ + R0 + ar) * 16 + ko);
      float4 a = fp[0], bq = fp[1];
      af8[0] = f2bf(a.x); af8[1] = f2bf(a.y); af8[2] = f2bf(a.z); af8[3] = f2bf(a.w);
      af8[4] = f2bf(bq.x); af8[5] = f2bf(bq.y); af8[6] = f2bf(bq.z); af8[7] = f2bf(bq.w);
    }
    short8v afO0 = *(const short8v*)&hsl[ar * 88 + ko];
    short8v afO1 = *(const short8v*)&hsl[ar * 88 + 32 + ko];

    f32x4 acc[4];
#pragma unroll
    for (int nt = 0; nt < 4; nt++) acc[nt] = (f32x4){0.f, 0.f, 0.f, 0.f};
#pragma unroll
    for (int nt = 0; nt < 4; nt++)
      acc[nt] = __builtin_amdgcn_mfma_f32_16x16x32_bf16(af8, bf[nt][8], acc[nt], 0, 0, 0);
#pragma unroll
    for (int nt = 0; nt < 4; nt++)
      acc[nt] = __builtin_amdgcn_mfma_f32_16x16x32_bf16(afO0, bf[nt][kfOwn], acc[nt], 0, 0, 0);
#pragma unroll
    for (int nt = 0; nt < 4; nt++)
      acc[nt] = __builtin_amdgcn_mfma_f32_16x16x32_bf16(afO1, bf[nt][kfOwn + 1], acc[nt], 0, 0, 0);

    // ---- wave-level poll: peers' h(t) ready (flag >= t+1)
    {
      const unsigned need = (unsigned)(t + 1);
      bool ok; long guard = 0;
      do {
        unsigned v = (lane < 4)
            ? __hip_atomic_load(pollp, __ATOMIC_RELAXED, __HIP_MEMORY_SCOPE_AGENT)
            : need;
        ok = __all((int)(v >= need));
        if (!ok) __builtin_amdgcn_s_sleep(1);
      } while (!ok && ++guard < (1L << 20));
      __builtin_amdgcn_fence(__ATOMIC_ACQUIRE, "agent");
    }

    // ---- peer h slices (6 remaining K-frags) + MFMA
    const unsigned long long* hrow =
        (const unsigned long long*)(hbr + (R0 + ar) * 128);
#pragma unroll
    for (int i = 0; i < 6; i++) {
      int kf = (i < kfOwn) ? i : i + 2;
      int kq = kf * 8 + (ko >> 2);
      union { unsigned long long q[2]; short8v s; } u;
      u.q[0] = __hip_atomic_load(hrow + kq, __ATOMIC_RELAXED, __HIP_MEMORY_SCOPE_AGENT);
      u.q[1] = __hip_atomic_load(hrow + kq + 1, __ATOMIC_RELAXED, __HIP_MEMORY_SCOPE_AGENT);
#pragma unroll
      for (int nt = 0; nt < 4; nt++)
        acc[nt] = __builtin_amdgcn_mfma_f32_16x16x32_bf16(u.s, bf[nt][kf], acc[nt], 0, 0, 0);
    }

    const int rb = (lane >> 4) * 4;
#pragma unroll
    for (int nt = 0; nt < 4; nt++)
#pragma unroll
      for (int rr = 0; rr < 4; rr++)
        gates[(rb + rr) * 256 + wv * 64 + nt * 16 + col15] = acc[nt][rr];
    __syncthreads();

    // ---- elementwise LSTM cell + h publish + fused head partial
#pragma unroll
    for (int p = 0; p < 2; p++) {
      int r = er + 8 * p;
      float hn2[2];
      float2 gi = *(const float2*)&gates[r * 256 + dl2];
      float2 gf = *(const float2*)&gates[r * 256 + 64 + dl2];
      float2 gg = *(const float2*)&gates[r * 256 + 128 + dl2];
      float2 go = *(const float2*)&gates[r * 256 + 192 + dl2];
      {
        float cn = sigm(gf.x + bsr[1][0]) * cst[p][0] +
                   sigm(gi.x + bsr[0][0]) * tanh_f(gg.x + bsr[2][0]);
        cst[p][0] = cn;
        hn2[0] = sigm(go.x + bsr[3][0]) * tanh_f(cn);
      }
      {
        float cn = sigm(gf.y + bsr[1][1]) * cst[p][1] +
                   sigm(gi.y + bsr[0][1]) * tanh_f(gg.y + bsr[2][1]);
        cst[p][1] = cn;
        hn2[1] = sigm(go.y + bsr[3][1]) * tanh_f(cn);
      }
      unsigned pk = (unsigned)f2bf(hn2[0]) | ((unsigned)f2bf(hn2[1]) << 16);
      __hip_atomic_store(hbw + (R0 + r) * 128 + ((D0 + dl2) >> 1), pk,
                         __ATOMIC_RELAXED, __HIP_MEMORY_SCOPE_AGENT);
      *(unsigned*)&hsl[r * 88 + dl2] = pk;
      float s = hn2[0] * hwr[0] + hn2[1] * hwr[1];
#pragma unroll
      for (int off = 16; off >= 1; off >>= 1) s += __shfl_xor(s, off);
      if ((lane & 31) == 0) atomicAdd(&out[(long)(R0 + r) * T_ + t], s);
    }

    __syncthreads();   // drains vmcnt: h(t+1) stores acked; protects hsl/gates
    if (tid == 0)
      __hip_atomic_store(myflag, (unsigned)(t + 2),
                         __ATOMIC_RELEASE, __HIP_MEMORY_SCOPE_AGENT);
    { unsigned* tmp = hbr; hbr = hbw; hbw = tmp; }
  }
}

// ---------------------------------------------------------------------------
extern "C" void kernel_launch(void* const* d_in, const int* in_sizes, int n_in,
                              void* d_out, int out_size, void* d_ws, size_t ws_size,
                              hipStream_t stream) {
  const float* x   = (const float*)d_in[0];
  const float* c1w = (const float*)d_in[1];
  const float* c1b = (const float*)d_in[2];
  const float* c2w = (const float*)d_in[3];
  const float* c2b = (const float*)d_in[4];
  const float* fcw = (const float*)d_in[5];
  const float* fcb = (const float*)d_in[6];
  const float* wih = (const float*)d_in[7];
  const float* whh = (const float*)d_in[8];
  const float* bih = (const float*)d_in[9];
  const float* bhh = (const float*)d_in[10];
  const float* hw  = (const float*)d_in[11];
  const float* hdb = (const float*)d_in[12];
  const float* h0  = (const float*)d_in[13];
  const float* c0  = (const float*)d_in[14];
  float* out = (float*)d_out;

  char* ws = (char*)d_ws;
  // layout: feat fp32 [270][128][16] | hbuf0 | hbuf1 (bf16 pairs) | flags
  const size_t FEAT_B = (size_t)T_ * B_ * 16 * 4;          // 2,211,840
  const size_t HBUF_B = (size_t)B_ * 128 * 4;              // 65,536
  if (ws_size < FEAT_B + 2 * HBUF_B + 4096) return;
  float* feat     = (float*)ws;
  unsigned* hb0   = (unsigned*)(ws + FEAT_B);
  unsigned* hb1   = (unsigned*)(ws + FEAT_B + HBUF_B);
  unsigned* flags = (unsigned*)(ws + FEAT_B + 2 * HBUF_B);

  cnn_kernel<<<dim3(B_ * T_), dim3(256), 0, stream>>>(
      x, c1w, c1b, c2w, c2b, fcw, fcb, hdb, feat, flags, out);
  lstm_kernel<<<dim3(32), dim3(256), 0, stream>>>(
      feat, whh, wih, bih, bhh, h0, c0, hw, hb0, hb1, flags, out);
}

// Round 3
// 1354.583 us; speedup vs baseline: 1.8976x; 1.8976x over previous
//
#include <hip/hip_runtime.h>

#define B_ 128
#define T_ 270
#define XR 4104   // 8 + 64*64

typedef __attribute__((ext_vector_type(8))) short short8v;
typedef __attribute__((ext_vector_type(4))) float f32x4;

__device__ inline unsigned short f2bf(float f) {
  unsigned u = __builtin_bit_cast(unsigned, f);
  u += 0x7fffu + ((u >> 16) & 1u);
  return (unsigned short)(u >> 16);
}
__device__ inline float sigm(float x) { return 1.0f / (1.0f + __expf(-x)); }
__device__ inline float tanh_f(float x) {
  float t = __expf(-2.0f * fabsf(x));
  float r = (1.0f - t) / (1.0f + t);
  return copysignf(r, x);
}

// ---------------------------------------------------------------------------
// Kernel 1: per-(b,t) CNN tower. One block per image.
// ---------------------------------------------------------------------------
__global__ __launch_bounds__(256) void cnn_kernel(
    const float* __restrict__ x,
    const float* __restrict__ c1w_, const float* __restrict__ c1b_,
    const float* __restrict__ c2w_, const float* __restrict__ c2b_,
    const float* __restrict__ fcw, const float* __restrict__ fcb,
    const float* __restrict__ hdb,
    float* __restrict__ feat, unsigned* __restrict__ flags,
    float* __restrict__ out)
{
  __shared__ float img[64 * 68];
  __shared__ float p1[2 * 15 * 16];
  __shared__ float p2[36];
  __shared__ float wsm[96];
  const int tid = threadIdx.x;
  const int bt = blockIdx.x;
  const int b = bt & 127, t = bt >> 7;

  if (bt == 0 && tid < 32) flags[tid * 16] = 0;   // re-zero step flags per launch

  const float* src = x + ((long)b * T_ + t) * XR;

  if (tid < 18) wsm[tid] = c1w_[tid];
  else if (tid < 20) wsm[tid] = c1b_[tid - 18];
  else if (tid < 92) wsm[tid] = c2w_[tid - 20];
  else if (tid < 96) wsm[tid] = c2b_[tid - 92];

  {
    const float4* s4 = (const float4*)(src + 8);
#pragma unroll
    for (int i0 = 0; i0 < 4; i0++) {
      int i = tid + i0 * 256;
      float4 v = s4[i];
      int e = i * 4;
      *((float4*)&img[(e >> 6) * 68 + (e & 63)]) = v;
    }
  }
  __syncthreads();

  if (tid < 225) {
    int py = tid / 15, px = tid - (tid / 15) * 15;
    float w0[9], w1[9];
#pragma unroll
    for (int j = 0; j < 9; j++) { w0[j] = wsm[j]; w1[j] = wsm[9 + j]; }
    const float b0 = wsm[18], b1v = wsm[19];
    float m0 = -1e30f, m1 = -1e30f;
    for (int dy = 0; dy < 4; dy++) {
      for (int dx = 0; dx < 4; dx++) {
        const float* ip = &img[(py * 4 + dy) * 68 + px * 4 + dx];
        float s0 = b0, s1 = b1v;
#pragma unroll
        for (int ky = 0; ky < 3; ky++) {
#pragma unroll
          for (int kx = 0; kx < 3; kx++) {
            float v = ip[ky * 68 + kx];
            s0 = fmaf(v, w0[ky * 3 + kx], s0);
            s1 = fmaf(v, w1[ky * 3 + kx], s1);
          }
        }
        m0 = fmaxf(m0, s0); m1 = fmaxf(m1, s1);
      }
    }
    p1[py * 16 + px] = fmaxf(m0, 0.f);
    p1[240 + py * 16 + px] = fmaxf(m1, 0.f);
  }
  __syncthreads();

  if (tid < 36) {
    int ch = tid / 9, rem = tid - ch * 9;
    int py = rem / 3, px = rem - py * 3;
    float m = -1e30f;
    for (int dy = 0; dy < 4; dy++) {
      for (int dx = 0; dx < 4; dx++) {
        int y = py * 4 + dy, xx = px * 4 + dx;
        float s = wsm[92 + ch];
#pragma unroll
        for (int ic = 0; ic < 2; ic++)
#pragma unroll
          for (int ky = 0; ky < 3; ky++)
#pragma unroll
            for (int kx = 0; kx < 3; kx++)
              s = fmaf(p1[ic * 240 + (y + ky) * 16 + xx + kx],
                       wsm[20 + ((ch * 2 + ic) * 3 + ky) * 3 + kx], s);
        m = fmaxf(m, s);
      }
    }
    p2[tid] = fmaxf(m, 0.f);
  }
  __syncthreads();

  float* fr = feat + ((long)t * B_ + b) * 16;
  if (tid < 8) {
    float s = fcb[tid];
#pragma unroll
    for (int j = 0; j < 36; j++) s = fmaf(p2[j], fcw[tid * 36 + j], s);
    fr[8 + tid] = s;
  } else if (tid < 16) {
    fr[tid - 8] = src[tid - 8];
  } else if (tid == 16) {
    out[(long)b * T_ + t] = hdb[0];
  }
}

// ---------------------------------------------------------------------------
// Kernel 2: LSTM recurrence. 32 blocks; gb = blk&7, hbk = blk>>3.
// Per-block K-fragment PERMUTATION: peer frags in slots 0..5, own in 6..7,
// feat/w_ih in 8 — so every register-array index is compile-time (rule #20;
// round-2's runtime bf[nt][kf] spilled 144 VGPRs to scratch, VGPR 172->64).
// The runtime kf only enters ADDRESS arithmetic. MFMA K-order is sum-invariant.
// ---------------------------------------------------------------------------
__global__ __launch_bounds__(256, 1) void lstm_kernel(
    const float* __restrict__ feat, const float* __restrict__ whh,
    const float* __restrict__ wih, const float* __restrict__ bih,
    const float* __restrict__ bhh, const float* __restrict__ h0,
    const float* __restrict__ c0, const float* __restrict__ hw,
    unsigned* hb0, unsigned* hb1, unsigned* flags, float* __restrict__ out)
{
  const int tid = threadIdx.x;
  const int wv = tid >> 6, lane = tid & 63;
  const int gb = blockIdx.x & 7;      // batch group 0..7 (rows gb*16..+15)
  const int hbk = blockIdx.x >> 3;    // hidden tile 0..3 (dims hbk*64..+63)
  const int R0 = gb * 16, D0 = hbk * 64;
  __shared__ float gates[16 * 258];           // row stride 258: 2-way banks
  __shared__ unsigned short hsl[16 * 72];     // own h slice, stride 72: 2-way

  const int col15 = lane & 15, ko = (lane >> 4) * 8;
  const int kfOwn = 2 * hbk;

  // ---- B-fragments, permuted slots. All array indices compile-time.
  short8v bfP[4][6];   // peer h columns
  short8v bfO[4][2];   // own h columns
  short8v bfF[4];      // w_ih (feat) columns
#pragma unroll
  for (int nt = 0; nt < 4; nt++) {
    int gr = wv * 256 + D0 + nt * 16 + col15;
    const float* wr = whh + gr * 256;
#pragma unroll
    for (int s = 0; s < 6; s++) {
      int kfv = (s < kfOwn) ? s : s + 2;      // runtime value, address-only
      const float4* wp = (const float4*)(wr + kfv * 32 + ko);
      float4 a = wp[0], bq = wp[1];
      short8v v;
      v[0] = f2bf(a.x); v[1] = f2bf(a.y); v[2] = f2bf(a.z); v[3] = f2bf(a.w);
      v[4] = f2bf(bq.x); v[5] = f2bf(bq.y); v[6] = f2bf(bq.z); v[7] = f2bf(bq.w);
      bfP[nt][s] = v;
    }
#pragma unroll
    for (int s = 0; s < 2; s++) {
      const float4* wp = (const float4*)(wr + (kfOwn + s) * 32 + ko);
      float4 a = wp[0], bq = wp[1];
      short8v v;
      v[0] = f2bf(a.x); v[1] = f2bf(a.y); v[2] = f2bf(a.z); v[3] = f2bf(a.w);
      v[4] = f2bf(bq.x); v[5] = f2bf(bq.y); v[6] = f2bf(bq.z); v[7] = f2bf(bq.w);
      bfO[nt][s] = v;
    }
    short8v v = {0, 0, 0, 0, 0, 0, 0, 0};
    if (ko < 16) {   // w_ih: K slots 0..15 of the feat fragment
      const float4* wp = (const float4*)(wih + gr * 16 + ko);
      float4 a = wp[0], bq = wp[1];
      v[0] = f2bf(a.x); v[1] = f2bf(a.y); v[2] = f2bf(a.z); v[3] = f2bf(a.w);
      v[4] = f2bf(bq.x); v[5] = f2bf(bq.y); v[6] = f2bf(bq.z); v[7] = f2bf(bq.w);
    }
    bfF[nt] = v;
  }

  // ---- elementwise-thread mapping: rows er+{0,8}, dims dl2, dl2+1
  const int dl2 = (tid & 31) * 2, er = tid >> 5;
  float cst[2][2];
  float bsr[4][2], hwr[2];
#pragma unroll
  for (int g = 0; g < 4; g++) {
    int grr = g * 256 + D0 + dl2;
    bsr[g][0] = bih[grr] + bhh[grr];
    bsr[g][1] = bih[grr + 1] + bhh[grr + 1];
  }
  hwr[0] = hw[D0 + dl2]; hwr[1] = hw[D0 + dl2 + 1];
#pragma unroll
  for (int p = 0; p < 2; p++) {
    int r = er + 8 * p;
    cst[p][0] = c0[(R0 + r) * 256 + D0 + dl2];
    cst[p][1] = c0[(R0 + r) * 256 + D0 + dl2 + 1];
    unsigned lo = f2bf(h0[(R0 + r) * 256 + D0 + dl2]);
    unsigned hi = f2bf(h0[(R0 + r) * 256 + D0 + dl2 + 1]);
    unsigned pk = lo | (hi << 16);
    __hip_atomic_store(hb0 + (R0 + r) * 128 + ((D0 + dl2) >> 1), pk,
                       __ATOMIC_RELAXED, __HIP_MEMORY_SCOPE_AGENT);
    *(unsigned*)&hsl[r * 72 + dl2] = pk;
  }
  __syncthreads();   // drains vmcnt: h0 stores acked before flag
  unsigned* myflag = flags + (gb * 4 + hbk) * 16;
  if (tid == 0)
    __hip_atomic_store(myflag, 1u, __ATOMIC_RELEASE, __HIP_MEMORY_SCOPE_AGENT);

  unsigned* hbr = hb0;
  unsigned* hbw = hb1;
  const int ar = lane & 15;           // A-fragment row
  unsigned* pollp = flags + (gb * 4 + (lane & 3)) * 16;

  for (int t = 0; t < T_; t++) {
    // ---- feat A-frag (global, ready) + own-slice A-frags (LDS) — pre-poll
    short8v af8 = {0, 0, 0, 0, 0, 0, 0, 0};
    if (ko < 16) {
      const float4* fp = (const float4*)(feat + ((long)t * B_ + R0 + ar) * 16 + ko);
      float4 a = fp[0], bq = fp[1];
      af8[0] = f2bf(a.x); af8[1] = f2bf(a.y); af8[2] = f2bf(a.z); af8[3] = f2bf(a.w);
      af8[4] = f2bf(bq.x); af8[5] = f2bf(bq.y); af8[6] = f2bf(bq.z); af8[7] = f2bf(bq.w);
    }
    short8v afO0 = *(const short8v*)&hsl[ar * 72 + ko];
    short8v afO1 = *(const short8v*)&hsl[ar * 72 + 32 + ko];

    f32x4 acc[4];
#pragma unroll
    for (int nt = 0; nt < 4; nt++) acc[nt] = (f32x4){0.f, 0.f, 0.f, 0.f};
#pragma unroll
    for (int nt = 0; nt < 4; nt++)
      acc[nt] = __builtin_amdgcn_mfma_f32_16x16x32_bf16(af8, bfF[nt], acc[nt], 0, 0, 0);
#pragma unroll
    for (int nt = 0; nt < 4; nt++)
      acc[nt] = __builtin_amdgcn_mfma_f32_16x16x32_bf16(afO0, bfO[nt][0], acc[nt], 0, 0, 0);
#pragma unroll
    for (int nt = 0; nt < 4; nt++)
      acc[nt] = __builtin_amdgcn_mfma_f32_16x16x32_bf16(afO1, bfO[nt][1], acc[nt], 0, 0, 0);

    // ---- wave-level poll: peers' h(t) ready (flag >= t+1)
    {
      const unsigned need = (unsigned)(t + 1);
      bool ok; long guard = 0;
      do {
        unsigned v = (lane < 4)
            ? __hip_atomic_load(pollp, __ATOMIC_RELAXED, __HIP_MEMORY_SCOPE_AGENT)
            : need;
        ok = __all((int)(v >= need));
        if (!ok) __builtin_amdgcn_s_sleep(1);
      } while (!ok && ++guard < (1L << 20));
      __builtin_amdgcn_fence(__ATOMIC_ACQUIRE, "agent");
    }

    // ---- peer h slices (slots 0..5) + MFMA; B index compile-time
    const unsigned long long* hrow =
        (const unsigned long long*)(hbr + (R0 + ar) * 128);
#pragma unroll
    for (int s = 0; s < 6; s++) {
      int kfv = (s < kfOwn) ? s : s + 2;      // address-only runtime value
      int kq = kfv * 8 + (ko >> 2);
      union { unsigned long long q[2]; short8v s8; } u;
      u.q[0] = __hip_atomic_load(hrow + kq, __ATOMIC_RELAXED, __HIP_MEMORY_SCOPE_AGENT);
      u.q[1] = __hip_atomic_load(hrow + kq + 1, __ATOMIC_RELAXED, __HIP_MEMORY_SCOPE_AGENT);
#pragma unroll
      for (int nt = 0; nt < 4; nt++)
        acc[nt] = __builtin_amdgcn_mfma_f32_16x16x32_bf16(u.s8, bfP[nt][s], acc[nt], 0, 0, 0);
    }

    const int rb = (lane >> 4) * 4;
#pragma unroll
    for (int nt = 0; nt < 4; nt++)
#pragma unroll
      for (int rr = 0; rr < 4; rr++)
        gates[(rb + rr) * 258 + wv * 64 + nt * 16 + col15] = acc[nt][rr];
    __syncthreads();

    // ---- elementwise LSTM cell + h publish + fused head partial
#pragma unroll
    for (int p = 0; p < 2; p++) {
      int r = er + 8 * p;
      float hn2[2];
      float2 gi = *(const float2*)&gates[r * 258 + dl2];
      float2 gf = *(const float2*)&gates[r * 258 + 64 + dl2];
      float2 gg = *(const float2*)&gates[r * 258 + 128 + dl2];
      float2 go = *(const float2*)&gates[r * 258 + 192 + dl2];
      {
        float cn = sigm(gf.x + bsr[1][0]) * cst[p][0] +
                   sigm(gi.x + bsr[0][0]) * tanh_f(gg.x + bsr[2][0]);
        cst[p][0] = cn;
        hn2[0] = sigm(go.x + bsr[3][0]) * tanh_f(cn);
      }
      {
        float cn = sigm(gf.y + bsr[1][1]) * cst[p][1] +
                   sigm(gi.y + bsr[0][1]) * tanh_f(gg.y + bsr[2][1]);
        cst[p][1] = cn;
        hn2[1] = sigm(go.y + bsr[3][1]) * tanh_f(cn);
      }
      unsigned pk = (unsigned)f2bf(hn2[0]) | ((unsigned)f2bf(hn2[1]) << 16);
      __hip_atomic_store(hbw + (R0 + r) * 128 + ((D0 + dl2) >> 1), pk,
                         __ATOMIC_RELAXED, __HIP_MEMORY_SCOPE_AGENT);
      *(unsigned*)&hsl[r * 72 + dl2] = pk;
      float s = hn2[0] * hwr[0] + hn2[1] * hwr[1];
#pragma unroll
      for (int off = 16; off >= 1; off >>= 1) s += __shfl_xor(s, off);
      if ((lane & 31) == 0) atomicAdd(&out[(long)(R0 + r) * T_ + t], s);
    }

    __syncthreads();   // drains vmcnt: h(t+1) stores acked; protects hsl/gates
    if (tid == 0)
      __hip_atomic_store(myflag, (unsigned)(t + 2),
                         __ATOMIC_RELEASE, __HIP_MEMORY_SCOPE_AGENT);
    { unsigned* tmp = hbr; hbr = hbw; hbw = tmp; }
  }
}

// ---------------------------------------------------------------------------
extern "C" void kernel_launch(void* const* d_in, const int* in_sizes, int n_in,
                              void* d_out, int out_size, void* d_ws, size_t ws_size,
                              hipStream_t stream) {
  const float* x   = (const float*)d_in[0];
  const float* c1w = (const float*)d_in[1];
  const float* c1b = (const float*)d_in[2];
  const float* c2w = (const float*)d_in[3];
  const float* c2b = (const float*)d_in[4];
  const float* fcw = (const float*)d_in[5];
  const float* fcb = (const float*)d_in[6];
  const float* wih = (const float*)d_in[7];
  const float* whh = (const float*)d_in[8];
  const float* bih = (const float*)d_in[9];
  const float* bhh = (const float*)d_in[10];
  const float* hw  = (const float*)d_in[11];
  const float* hdb = (const float*)d_in[12];
  const float* h0  = (const float*)d_in[13];
  const float* c0  = (const float*)d_in[14];
  float* out = (float*)d_out;

  char* ws = (char*)d_ws;
  // layout: feat fp32 [270][128][16] | hbuf0 | hbuf1 (bf16 pairs) | flags
  const size_t FEAT_B = (size_t)T_ * B_ * 16 * 4;          // 2,211,840
  const size_t HBUF_B = (size_t)B_ * 128 * 4;              // 65,536
  if (ws_size < FEAT_B + 2 * HBUF_B + 4096) return;
  float* feat     = (float*)ws;
  unsigned* hb0   = (unsigned*)(ws + FEAT_B);
  unsigned* hb1   = (unsigned*)(ws + FEAT_B + HBUF_B);
  unsigned* flags = (unsigned*)(ws + FEAT_B + 2 * HBUF_B);

  cnn_kernel<<<dim3(B_ * T_), dim3(256), 0, stream>>>(
      x, c1w, c1b, c2w, c2b, fcw, fcb, hdb, feat, flags, out);
  lstm_kernel<<<dim3(32), dim3(256), 0, stream>>>(
      feat, whh, wih, bih, bhh, h0, c0, hw, hb0, hb1, flags, out);
}